// Round 2
// baseline (189.848 us; speedup 1.0000x reference)
//
#include <hip/hip_runtime.h>

// Problem constants
#define BB 256   // batch
#define HH 512   // hidden
#define CC 64    // spline channels
#define NN 100   // time knots
#define KT 8     // K_TERMS

typedef short s16x8 __attribute__((ext_vector_type(8)));
typedef float f32x4 __attribute__((ext_vector_type(4)));

#define MFMA16(a, b, c) __builtin_amdgcn_mfma_f32_16x16x32_bf16((a), (b), (c), 0, 0, 0)

static __device__ __forceinline__ unsigned short f2bf(float f) {
    union { float f; unsigned int u; } v; v.f = f;
    unsigned int r = v.u + 0x7FFFu + ((v.u >> 16) & 1u);  // RNE
    return (unsigned short)(r >> 16);
}

// ---------------------------------------------------------------------------
// A-frag layout for a 16-row x 512-col bf16 activation tile t (8192 halfwords):
//   F[t*8192 + g*512 + lane*8 + e] = M[lane&15][g*32 + (lane>>4)*8 + e]
// MFMA A-operand for Ktile g is a coalesced 16B/lane load at lane*8.
// For K=64 (x/xdot) tiles: 2 g-groups, 1024 halfwords per 16-row tile.
// ---------------------------------------------------------------------------

// ---------------------------------------------------------------------------
// k_pack: weight bf16 conversion into MFMA-frag-packed layout + h conversion
// into A-FRAG layout + cubic spline eval (x, xdot) directly into A-frag.
// ---------------------------------------------------------------------------
__global__ void k_pack(const float* __restrict__ wh, const float* __restrict__ wout,
                       const float* __restrict__ wx, const float* __restrict__ h,
                       const float* __restrict__ coeffs, const float* __restrict__ dcoeffs,
                       const float* __restrict__ tobs, const float* __restrict__ tg,
                       unsigned short* __restrict__ whp, unsigned short* __restrict__ wop,
                       unsigned short* __restrict__ wxp, unsigned short* __restrict__ hf,
                       unsigned short* __restrict__ xf, unsigned short* __restrict__ xdf) {
    int gid = blockIdx.x * 256 + threadIdx.x;
    if (gid < 524288) {                       // wh / wout packed (262144 each)
        const float* src = (gid < 262144) ? wh : wout;
        unsigned short* dst = (gid < 262144) ? whp : wop;
        int p = gid & 262143;
        int e = p & 7, lane = (p >> 3) & 63, g = (p >> 9) & 15, cg = (p >> 13) & 1, w = p >> 14;
        int row = w * 32 + cg * 16 + (lane & 15);
        int k = g * 32 + (lane >> 4) * 8 + e;
        dst[p] = f2bf(src[row * HH + k]);
    } else if (gid < 557056) {                // wx packed (32768)
        int p = gid - 524288;
        int e = p & 7, lane = (p >> 3) & 63, g = (p >> 9) & 1, cg = (p >> 10) & 1, w = p >> 11;
        int row = w * 32 + cg * 16 + (lane & 15);
        int k = g * 32 + (lane >> 4) * 8 + e;
        wxp[p] = f2bf(wx[row * CC + k]);
    } else if (gid < 688128) {                // h -> bf16 A-frag (131072)
        int p = gid - 557056;
        int e = p & 7, lane = (p >> 3) & 63, g = (p >> 9) & 15, btp = p >> 13;
        int row = btp * 16 + (lane & 15);
        int k = g * 32 + (lane >> 4) * 8 + e;
        hf[p] = f2bf(h[row * HH + k]);
    } else if (gid < 704512) {                // spline eval -> A-frag (16384)
        int p = gid - 688128;
        int b = p >> 6, c = p & 63;
        float t = tg[0];
        int cntv = 0;
        for (int n = 0; n < NN; n++) cntv += (tobs[n] <= t) ? 1 : 0;
        int idx = cntv - 1;
        idx = idx < 0 ? 0 : (idx > NN - 2 ? NN - 2 : idx);  // clip to [0, 98]
        float dt = t - tobs[idx];
        const float* cb = coeffs + ((size_t)(b * (NN - 1) + idx) * 4) * CC + c;
        float xv = cb[0] + dt * (cb[CC] + dt * (cb[2 * CC] + dt * cb[3 * CC]));
        const float* db = dcoeffs + ((size_t)(b * (NN - 1) + idx) * 4) * CC + c;
        float xd = db[0] + dt * (db[CC] + dt * (db[2 * CC] + dt * db[3 * CC]));
        // frag index for M[b&15][c] within tile b>>4 (K=64: 2 g-groups)
        int fi = (b >> 4) * 1024 + (c >> 5) * 512 + ((b & 15) + ((c >> 3) & 3) * 16) * 8 + (c & 7);
        xf[fi] = f2bf(xv);
        xdf[fi] = f2bf(xd);
    }
}

// ---------------------------------------------------------------------------
// k_fused: the ENTIRE network in one persistent kernel. 16 blocks (one per
// 16-row batch tile) x 512 threads (8 waves; wave w owns cols [w*64,w*64+64)).
// Phases (each streams one 512KB weight matrix from L2, ~4.4us):
//   L1:  l1 = h@wh^T + x@wx^T + b0 -> relu frag -> sa[0]; dr=sigmoid(l1) regs;
//        s0 = dr*(xdot@wx^T) frag -> sa[1]   (xdot GEMM shares wx B-frags)
//   TH:  z = relu@wout^T + b1 -> th=tanh, dt=1-th^2 (regs);
//        curr0 = dt*(s0@wout^T) -> hd regs + frag -> sa[0]
//        (both GEMMs share the wout B-frag stream)
//   Neumann p=0..15: alternating s=dr*(curr@wh^T) / curr'=dt*(s@wout^T),
//        curr ping-pongs sa[0]<->sa[1], ONE __syncthreads per phase.
// No global intermediates at all; only outp is written.
// ---------------------------------------------------------------------------
__global__ __launch_bounds__(512) void k_fused(
    const unsigned short* __restrict__ whp, const unsigned short* __restrict__ wop,
    const unsigned short* __restrict__ wxp, const unsigned short* __restrict__ hf,
    const unsigned short* __restrict__ xf, const unsigned short* __restrict__ xdf,
    const float* __restrict__ b0g, const float* __restrict__ b1g,
    float* __restrict__ outp) {
    __shared__ __align__(16) unsigned short sa[2][8192];  // ping-pong A-frag (16KB each)
    const int tid = threadIdx.x;
    const int w = tid >> 6, lane = tid & 63;
    const int col2 = lane & 15, kq = lane >> 4;
    const int bt = blockIdx.x;

    // per-thread column constants: biases + LDS frag write base (r=0)
    //   pos(m=kq*4+r, k=c) = (c>>5)*512 + (c&7) + (((c>>3)&3)<<7) + m*8
    float b0v[4], b1v[4];
    int fb[4];
#pragma unroll
    for (int t = 0; t < 4; t++) {
        const int c = (w * 4 + t) * 16 + col2;
        b0v[t] = b0g[c];
        b1v[t] = b1g[c];
        fb[t] = ((w * 4 + t) >> 1) * 512 + (col2 & 7) + (((t * 2 + (col2 >> 3)) & 3) << 7) + kq * 32;
    }

    // wave's B-frag bases: tile ct=w*4+t, frag (ct,g) at ((ct*16+g)*64+lane) s16x8
    const s16x8* wlh = (const s16x8*)whp + (size_t)w * 4096 + lane;
    const s16x8* wlo = (const s16x8*)wop + (size_t)w * 4096 + lane;

    float dr[4][4], dt[4][4], hd[4][4];

    // ---------------- Phase L1 ----------------
    {
        const s16x8* ha = (const s16x8*)(hf + (size_t)bt * 8192) + lane;
        f32x4 acc[4] = {{0.f, 0.f, 0.f, 0.f}, {0.f, 0.f, 0.f, 0.f},
                        {0.f, 0.f, 0.f, 0.f}, {0.f, 0.f, 0.f, 0.f}};
        f32x4 vac[4] = {{0.f, 0.f, 0.f, 0.f}, {0.f, 0.f, 0.f, 0.f},
                        {0.f, 0.f, 0.f, 0.f}, {0.f, 0.f, 0.f, 0.f}};
        s16x8 bfr[2][4], af[2];
        af[0] = ha[0];
#pragma unroll
        for (int t = 0; t < 4; t++) bfr[0][t] = wlh[t * 1024];
#pragma unroll
        for (int g = 0; g < 16; g++) {
            if (g < 15) {
                af[(g + 1) & 1] = ha[(g + 1) * 64];
#pragma unroll
                for (int t = 0; t < 4; t++) bfr[(g + 1) & 1][t] = wlh[t * 1024 + (g + 1) * 64];
            }
#pragma unroll
            for (int t = 0; t < 4; t++) acc[t] = MFMA16(af[g & 1], bfr[g & 1][t], acc[t]);
        }
#pragma unroll
        for (int g = 0; g < 2; g++) {
            const s16x8 xa = *((const s16x8*)(xf + (size_t)bt * 1024 + g * 512) + lane);
            const s16x8 xda = *((const s16x8*)(xdf + (size_t)bt * 1024 + g * 512) + lane);
#pragma unroll
            for (int t = 0; t < 4; t++) {
                const s16x8 bf = ((const s16x8*)wxp)[(size_t)((w * 4 + t) * 2 + g) * 64 + lane];
                acc[t] = MFMA16(xa, bf, acc[t]);
                vac[t] = MFMA16(xda, bf, vac[t]);
            }
        }
        // epilogue: relu frag -> sa[0], s0 frag -> sa[1], dr -> regs
#pragma unroll
        for (int t = 0; t < 4; t++)
#pragma unroll
            for (int r = 0; r < 4; r++) {
                const float l1 = acc[t][r] + b0v[t];
                const float dra = 1.f / (1.f + expf(-l1));
                dr[t][r] = dra;
                sa[0][fb[t] + r * 8] = f2bf(fmaxf(l1, 0.f));
                sa[1][fb[t] + r * 8] = f2bf(dra * vac[t][r]);
            }
    }
    __syncthreads();  // relu/s0 frags visible

    // ---------------- Phase TH ----------------
    {
        const unsigned short* A0 = &sa[0][lane * 8];
        const unsigned short* A1 = &sa[1][lane * 8];
        f32x4 acc[4] = {{0.f, 0.f, 0.f, 0.f}, {0.f, 0.f, 0.f, 0.f},
                        {0.f, 0.f, 0.f, 0.f}, {0.f, 0.f, 0.f, 0.f}};
        f32x4 cac[4] = {{0.f, 0.f, 0.f, 0.f}, {0.f, 0.f, 0.f, 0.f},
                        {0.f, 0.f, 0.f, 0.f}, {0.f, 0.f, 0.f, 0.f}};
        s16x8 bfr[2][4];
#pragma unroll
        for (int t = 0; t < 4; t++) bfr[0][t] = wlo[t * 1024];
#pragma unroll
        for (int g = 0; g < 16; g++) {
            if (g < 15) {
#pragma unroll
                for (int t = 0; t < 4; t++) bfr[(g + 1) & 1][t] = wlo[t * 1024 + (g + 1) * 64];
            }
            const s16x8 ar = *(const s16x8*)(A0 + (size_t)g * 512);
            const s16x8 as = *(const s16x8*)(A1 + (size_t)g * 512);
#pragma unroll
            for (int t = 0; t < 4; t++) {
                acc[t] = MFMA16(ar, bfr[g & 1][t], acc[t]);
                cac[t] = MFMA16(as, bfr[g & 1][t], cac[t]);
            }
        }
        __syncthreads();  // all waves done READING sa[0]/sa[1]
#pragma unroll
        for (int t = 0; t < 4; t++)
#pragma unroll
            for (int r = 0; r < 4; r++) {
                const float th = tanhf(acc[t][r] + b1v[t]);
                const float dtv = 1.f - th * th;
                dt[t][r] = dtv;
                const float c0 = dtv * cac[t][r];
                hd[t][r] = c0;
                sa[0][fb[t] + r * 8] = f2bf(c0);  // curr0 frag (Neumann p=0 input)
            }
    }
    __syncthreads();  // curr0 frag visible

    // ---------------- Neumann loop ----------------
    const unsigned short* A0 = &sa[0][lane * 8];
    const unsigned short* A1 = &sa[1][lane * 8];
    for (int p = 0; p < 16; p++) {
        const s16x8* wl = (p & 1) ? wlo : wlh;          // even: wh, odd: wout
        const unsigned short* Ar = (p & 1) ? A1 : A0;   // read sa[p&1]
        f32x4 acc[4] = {{0.f, 0.f, 0.f, 0.f}, {0.f, 0.f, 0.f, 0.f},
                        {0.f, 0.f, 0.f, 0.f}, {0.f, 0.f, 0.f, 0.f}};
        s16x8 bfr[2][4];
#pragma unroll
        for (int t = 0; t < 4; t++) bfr[0][t] = wl[t * 1024];
#pragma unroll
        for (int g = 0; g < 16; g++) {
            if (g < 15) {
#pragma unroll
                for (int t = 0; t < 4; t++) bfr[(g + 1) & 1][t] = wl[t * 1024 + (g + 1) * 64];
            }
            const s16x8 a = *(const s16x8*)(Ar + (size_t)g * 512);
#pragma unroll
            for (int t = 0; t < 4; t++) acc[t] = MFMA16(a, bfr[g & 1][t], acc[t]);
        }
        unsigned short* Aw = &sa[(p + 1) & 1][0];       // write the other buffer
        if (p & 1) {            // wout phase: curr' = dtanh*(s@wout^T); h_dot += curr'
            if (p < 15) {
#pragma unroll
                for (int t = 0; t < 4; t++)
#pragma unroll
                    for (int r = 0; r < 4; r++) {
                        float v = dt[t][r] * acc[t][r];
                        hd[t][r] += v;
                        Aw[fb[t] + r * 8] = f2bf(v);
                    }
            } else {
#pragma unroll
                for (int t = 0; t < 4; t++)
#pragma unroll
                    for (int r = 0; r < 4; r++) hd[t][r] += dt[t][r] * acc[t][r];
            }
        } else {                // wh phase: s = drelu*(curr@wh^T)
#pragma unroll
            for (int t = 0; t < 4; t++)
#pragma unroll
                for (int r = 0; r < 4; r++)
                    Aw[fb[t] + r * 8] = f2bf(dr[t][r] * acc[t][r]);
        }
        if (p < 15) __syncthreads();  // one barrier per phase (double-buffer => no lapping)
    }

#pragma unroll
    for (int t = 0; t < 4; t++) {
        const int c = (w * 4 + t) * 16 + col2;
#pragma unroll
        for (int r = 0; r < 4; r++)
            outp[(size_t)(bt * 16 + kq * 4 + r) * HH + c] = hd[t][r];
    }
}

// ---------------------------------------------------------------------------
extern "C" void kernel_launch(void* const* d_in, const int* in_sizes, int n_in,
                              void* d_out, int out_size, void* d_ws, size_t ws_size,
                              hipStream_t stream) {
    const float* tg = (const float*)d_in[0];
    const float* h = (const float*)d_in[1];
    const float* coeffs = (const float*)d_in[2];
    const float* dcoeffs = (const float*)d_in[3];
    const float* tobs = (const float*)d_in[4];
    const float* wx = (const float*)d_in[5];
    const float* wh = (const float*)d_in[6];
    const float* wout = (const float*)d_in[7];
    const float* b0g = (const float*)d_in[8];
    const float* b1g = (const float*)d_in[9];
    float* outp = (float*)d_out;

    char* ws = (char*)d_ws;
    unsigned short* whp = (unsigned short*)(ws + 0);        // 512KB packed bf16
    unsigned short* wop = (unsigned short*)(ws + 524288);   // 512KB
    unsigned short* wxp = (unsigned short*)(ws + 1048576);  // 64KB
    unsigned short* hf  = (unsigned short*)(ws + 1114112);  // 256KB h A-frag
    unsigned short* xf  = (unsigned short*)(ws + 1376256);  // 32KB x A-frag
    unsigned short* xdf = (unsigned short*)(ws + 1409024);  // 32KB xdot A-frag

    k_pack<<<2752, 256, 0, stream>>>(wh, wout, wx, h, coeffs, dcoeffs, tobs, tg,
                                     whp, wop, wxp, hf, xf, xdf);
    k_fused<<<16, 512, 0, stream>>>(whp, wop, wxp, hf, xf, xdf, b0g, b1g, outp);
}